// Round 2
// baseline (2578.064 us; speedup 1.0000x reference)
//
#include <hip/hip_runtime.h>
#include <hip/hip_bf16.h>

// CRF forward on MI355X — R1: latency-optimized sequential scan.
// One block per batch, thread k owns state k. E=exp(trans) in registers (fp16x2).
// Per step: q = E·V (dot2), V' = exp(y)*q*2^-sigma, sigma from PREVIOUS step's max
// (exact deferred normalization, scale tracked in log2). Double-buffered V and mred
// -> ONE barrier per step; DPP wave-max (VALU pipe) instead of ds_swizzle butterfly.

typedef _Float16 h2 __attribute__((ext_vector_type(2)));
typedef _Float16 h8 __attribute__((ext_vector_type(8)));

#define TT 2048
#define KK 256
#define NTHREADS 256
#define SOS_IDX 2
#define C2 9.0f      // constant log2 headroom: stored max ~ 2^(c_t - 9), bounded for fp16

#if __has_builtin(__builtin_amdgcn_fdot2)
#define FDOT2(a, b, c) __builtin_amdgcn_fdot2((a), (b), (c), false)
#else
#define FDOT2(a, b, c) ((c) + (float)(a)[0] * (float)(b)[0] + (float)(a)[1] * (float)(b)[1])
#endif

// DPP max step: lane i takes max with lane shifted per CTRL (VALU pipe, no LDS).
// old=0 for out-of-bounds lanes is safe: all reduced values are >= 0.
template<int CTRL>
__device__ __forceinline__ float maxdpp(float x) {
    int s = __builtin_amdgcn_update_dpp(0, __float_as_int(x), CTRL, 0xF, 0xF, false);
    return fmaxf(x, __int_as_float(s));
}

// 64-lane max; result valid in lane 63.
__device__ __forceinline__ float wave_max64(float x) {
    x = maxdpp<0x111>(x);  // row_shr:1
    x = maxdpp<0x112>(x);  // row_shr:2
    x = maxdpp<0x114>(x);  // row_shr:4
    x = maxdpp<0x118>(x);  // row_shr:8
    x = maxdpp<0x142>(x);  // row_bcast:15
    x = maxdpp<0x143>(x);  // row_bcast:31
    return x;
}

__global__ __launch_bounds__(NTHREADS, 1)
void crf_fwd_kernel(const float* __restrict__ y, const float* __restrict__ mask,
                    const float* __restrict__ trans, float* __restrict__ out) {
    const int b = blockIdx.x;
    const int k = threadIdx.x;
    const int lane = k & 63;
    const int wave = k >> 6;

    __shared__ __align__(16) _Float16 Pb[2][KK];   // double-buffered prob vector (fp16)
    __shared__ __align__(16) float mred[2][4];     // double-buffered per-wave maxes
    __shared__ float sred[8];                      // startup/epilogue scratch

    // ---- E row k = exp(trans[k,:]) resident in registers (128 packed fp16 pairs)
    h2 e[KK / 2];
    {
        const float4* tr = (const float4*)(trans + (size_t)k * KK);
        #pragma unroll
        for (int i = 0; i < KK / 4; ++i) {
            float4 v = tr[i];
            h2 a, c;
            a[0] = (_Float16)__expf(v.x);
            a[1] = (_Float16)__expf(v.y);
            c[0] = (_Float16)__expf(v.z);
            c[1] = (_Float16)__expf(v.w);
            e[2 * i]     = a;
            e[2 * i + 1] = c;
        }
    }

    // ---- L = sum(mask[b,:])  (mask monotone)
    float lsum = 0.f;
    {
        const float* mrow = mask + (size_t)b * TT;
        #pragma unroll
        for (int i = 0; i < TT / NTHREADS; ++i) lsum += mrow[k + i * NTHREADS];
        #pragma unroll
        for (int off = 32; off >= 1; off >>= 1) lsum += __shfl_xor(lsum, off, 64);
        if (lane == 0) sred[wave] = lsum;
    }

    // ---- init: V0 = one-hot(SOS); prime mred[0] so lambda_0 = log2(1) = 0
    float pf = (k == SOS_IDX) ? 1.f : 0.f;
    Pb[0][k] = (_Float16)pf;
    if (k < 4) mred[0][k] = 1.0f;
    __syncthreads();
    const int L = (int)(sred[0] + sred[1] + sred[2] + sred[3] + 0.5f);

    const float* yrow = y + (size_t)b * TT * KK + k;
    float ycur = (L > 0) ? yrow[0] : 0.f;
    float ey = __expf(ycur);      // exp of emission, precomputed off-path
    float Lam = 0.f;              // accumulated log2 scale (wave-uniform)
    int cur = 0;

    for (int t = 0; t < L; ++t) {
        const int nxt = cur ^ 1;

        // issue early: previous step's per-wave maxes + next emission (latency
        // hidden under the dot's LDS reads)
        float4 mr = *(const float4*)mred[cur];
        float ynext = (t + 1 < L) ? yrow[(size_t)(t + 1) * KK] : 0.f;

        // q_k = dot(E[k,:], V[:]) — 128 dot2, 8 accumulators (16-deep chains)
        float qa0 = 0.f, qa1 = 0.f, qa2 = 0.f, qa3 = 0.f;
        float qb0 = 0.f, qb1 = 0.f, qb2 = 0.f, qb3 = 0.f;
        const h8* Pv = (const h8*)Pb[cur];
        #pragma unroll
        for (int c = 0; c < KK / 16; ++c) {
            h8 pva = Pv[2 * c];
            h8 pvb = Pv[2 * c + 1];
            h2 a0 = {pva[0], pva[1]}, a1 = {pva[2], pva[3]};
            h2 a2 = {pva[4], pva[5]}, a3 = {pva[6], pva[7]};
            h2 b0 = {pvb[0], pvb[1]}, b1 = {pvb[2], pvb[3]};
            h2 b2 = {pvb[4], pvb[5]}, b3 = {pvb[6], pvb[7]};
            qa0 = FDOT2(e[8 * c + 0], a0, qa0);
            qa1 = FDOT2(e[8 * c + 1], a1, qa1);
            qa2 = FDOT2(e[8 * c + 2], a2, qa2);
            qa3 = FDOT2(e[8 * c + 3], a3, qa3);
            qb0 = FDOT2(e[8 * c + 4], b0, qb0);
            qb1 = FDOT2(e[8 * c + 5], b1, qb1);
            qb2 = FDOT2(e[8 * c + 6], b2, qb2);
            qb3 = FDOT2(e[8 * c + 7], b3, qb3);
        }
        float q = ((qa0 + qa1) + (qa2 + qa3)) + ((qb0 + qb1) + (qb2 + qb3));

        // wave-uniform scale from PREVIOUS step's max (exact bookkeeping)
        float M = fmaxf(fmaxf(mr.x, mr.y), fmaxf(mr.z, mr.w));  // = max(V_t)
        float sigma = __log2f(M) + C2;
        float f = exp2f(-sigma);
        Lam += sigma;

        // V'_k = exp(y)*q*2^-sigma ; store immediately, reduce after (off path)
        float pn = ey * q * f;
        Pb[nxt][k] = (_Float16)pn;
        pf = pn;

        float wm = wave_max64(pn);                 // DPP, VALU pipe
        if (lane == 63) mred[nxt][wave] = wm;

        ey = __expf(ynext);                        // off-path prep for next step
        cur = nxt;
        __syncthreads();                           // single barrier per step
    }

    // ---- out[b] = ln2 * (Lam + log2(sum_k V_k))
    float ssum = pf;
    #pragma unroll
    for (int off = 32; off >= 1; off >>= 1) ssum += __shfl_xor(ssum, off, 64);
    if (lane == 0) sred[4 + wave] = ssum;
    __syncthreads();
    if (k == 0) {
        float tot = (sred[4] + sred[5]) + (sred[6] + sred[7]);
        out[b] = 0.69314718056f * (Lam + __log2f(tot));
    }
}

extern "C" void kernel_launch(void* const* d_in, const int* in_sizes, int n_in,
                              void* d_out, int out_size, void* d_ws, size_t ws_size,
                              hipStream_t stream) {
    const float* y     = (const float*)d_in[0];   // (B, T, K) fp32
    const float* mask  = (const float*)d_in[1];   // (B, T)    fp32
    const float* trans = (const float*)d_in[2];   // (K, K)    fp32
    float* out = (float*)d_out;                   // (B,)      fp32
    const int B = in_sizes[1] / TT;
    crf_fwd_kernel<<<B, NTHREADS, 0, stream>>>(y, mask, trans, out);
}

// Round 3
// 1759.245 us; speedup vs baseline: 1.4654x; 1.4654x over previous
//
#include <hip/hip_runtime.h>
#include <hip/hip_bf16.h>

// CRF forward on MI355X — R2: zero-cross-lane steady state.
// Every thread reads all of V anyway (for its dot), so every thread redundantly
// computes the block normalizer S = sum(V) itself: no shuffle butterfly, no DPP,
// no reduction round-trip — one barrier per step (double-buffered V).
// Scale per step: V' = exp(y) * (E·V) * 2^-5 / S  (exact bookkeeping via rcp + log2).
// y staged in registers 8 steps at a time so the barrier's vmcnt(0) drain is
// load-free on 7 of 8 steps.

typedef _Float16 h2 __attribute__((ext_vector_type(2)));
typedef _Float16 h8 __attribute__((ext_vector_type(8)));

#define TT 2048
#define KK 256
#define NTHREADS 256
#define SOS_IDX 2
#define CH 8

#define FDOT2(a, b, c) __builtin_amdgcn_fdot2((a), (b), (c), false)

__global__ __launch_bounds__(NTHREADS, 1)
void crf_fwd_kernel(const float* __restrict__ y, const float* __restrict__ mask,
                    const float* __restrict__ trans, float* __restrict__ out) {
    const int b = blockIdx.x;
    const int k = threadIdx.x;
    const int lane = k & 63;
    const int wave = k >> 6;

    __shared__ __align__(16) _Float16 Pb[2][KK];  // double-buffered prob vector
    __shared__ float sred[4];

    // ---- E row k = exp(trans[k,:]) resident in registers (128 packed fp16 pairs)
    h2 e[KK / 2];
    {
        const float4* tr = (const float4*)(trans + (size_t)k * KK);
        #pragma unroll
        for (int i = 0; i < KK / 4; ++i) {
            float4 v = tr[i];
            h2 a, c;
            a[0] = (_Float16)__expf(v.x);
            a[1] = (_Float16)__expf(v.y);
            c[0] = (_Float16)__expf(v.z);
            c[1] = (_Float16)__expf(v.w);
            e[2 * i]     = a;
            e[2 * i + 1] = c;
        }
    }

    // ---- L = sum(mask[b,:])  (one-time; butterfly cost irrelevant here)
    float lsum = 0.f;
    {
        const float* mrow = mask + (size_t)b * TT;
        #pragma unroll
        for (int i = 0; i < TT / NTHREADS; ++i) lsum += mrow[k + i * NTHREADS];
        #pragma unroll
        for (int off = 32; off >= 1; off >>= 1) lsum += __shfl_xor(lsum, off, 64);
        if (lane == 0) sred[wave] = lsum;
    }

    // ---- init: V0 = one-hot(SOS)
    Pb[0][k] = (_Float16)((k == SOS_IDX) ? 1.f : 0.f);
    __syncthreads();
    const int L = (int)(sred[0] + sred[1] + sred[2] + sred[3] + 0.5f);

    const float* yrow = y + (size_t)b * TT * KK + k;
    float Lam = 0.f;          // sum of log2(S_t), wave-uniform
    int cur = 0;
    const h2 ones = {(_Float16)1.f, (_Float16)1.f};

    for (int t0 = 0; t0 < L; t0 += CH) {
        // stage next CH emissions in registers (coalesced; rows t0..t0+7 < T always
        // since t0 is a multiple of 8 and t0 < L <= 2048)
        float yv[CH];
        #pragma unroll
        for (int u = 0; u < CH; ++u) yv[u] = yrow[(size_t)(t0 + u) * KK];
        const int nst = (L - t0 < CH) ? (L - t0) : CH;

        #pragma unroll
        for (int u = 0; u < CH; ++u) {
            if (u < nst) {    // block-uniform
                float ey = __expf(yv[u]);   // off critical path

                float q0 = 0.f, q1 = 0.f, q2 = 0.f, q3 = 0.f;
                float s0 = 0.f, s1 = 0.f, s2 = 0.f, s3 = 0.f;
                const h8* Pv = (const h8*)Pb[cur];
                #pragma unroll
                for (int c = 0; c < KK / 8; ++c) {
                    h8 pv = Pv[c];   // broadcast ds_read_b128
                    h2 p0 = {pv[0], pv[1]}, p1 = {pv[2], pv[3]};
                    h2 p2 = {pv[4], pv[5]}, p3 = {pv[6], pv[7]};
                    q0 = FDOT2(e[4 * c + 0], p0, q0);
                    q1 = FDOT2(e[4 * c + 1], p1, q1);
                    q2 = FDOT2(e[4 * c + 2], p2, q2);
                    q3 = FDOT2(e[4 * c + 3], p3, q3);
                    s0 = FDOT2(ones, p0, s0);
                    s1 = FDOT2(ones, p1, s1);
                    s2 = FDOT2(ones, p2, s2);
                    s3 = FDOT2(ones, p3, s3);
                }
                float q = (q0 + q1) + (q2 + q3);
                float S = (s0 + s1) + (s2 + s3);   // block-wide sum, identical in all threads

                // scale = 2^-5 / S  (exact pairing: rcp for the scale, log2 for the books)
                float f = __builtin_amdgcn_rcpf(S) * 0.03125f;
                float pn = ey * q * f;
                Pb[cur ^ 1][k] = (_Float16)pn;
                Lam += __log2f(S);
                cur ^= 1;
                __syncthreads();
            }
        }
    }

    // ---- epilogue: S over final V (redundant per-thread, no reduce needed)
    {
        float s0 = 0.f, s1 = 0.f, s2 = 0.f, s3 = 0.f;
        const h8* Pv = (const h8*)Pb[cur];
        #pragma unroll
        for (int c = 0; c < KK / 8; ++c) {
            h8 pv = Pv[c];
            h2 p0 = {pv[0], pv[1]}, p1 = {pv[2], pv[3]};
            h2 p2 = {pv[4], pv[5]}, p3 = {pv[6], pv[7]};
            s0 = FDOT2(ones, p0, s0);
            s1 = FDOT2(ones, p1, s1);
            s2 = FDOT2(ones, p2, s2);
            s3 = FDOT2(ones, p3, s3);
        }
        float Sf = (s0 + s1) + (s2 + s3);
        if (k == 0) {
            // logZ = ln2 * (log2(sum V_L) + sum_t(log2 S_t + 5))
            out[b] = 0.69314718056f * (__log2f(Sf) + Lam + 5.0f * (float)L);
        }
    }
}

extern "C" void kernel_launch(void* const* d_in, const int* in_sizes, int n_in,
                              void* d_out, int out_size, void* d_ws, size_t ws_size,
                              hipStream_t stream) {
    const float* y     = (const float*)d_in[0];   // (B, T, K) fp32
    const float* mask  = (const float*)d_in[1];   // (B, T)    fp32
    const float* trans = (const float*)d_in[2];   // (K, K)    fp32
    float* out = (float*)d_out;                   // (B,)      fp32
    const int B = in_sizes[1] / TT;
    crf_fwd_kernel<<<B, NTHREADS, 0, stream>>>(y, mask, trans, out);
}